// Round 17
// baseline (100.002 us; speedup 1.0000x reference)
//
#include <hip/hip_runtime.h>
#include <cstdint>

#define NB 4
#define NQ 8192
#define NC 256
#define IH 128
#define IW 128
#define NHW (IH * IW)
#define NHEADS 8
#define NP 4
#define NHD 32

typedef __bf16 bf16x8 __attribute__((ext_vector_type(8)));
typedef float f32x4 __attribute__((ext_vector_type(4)));
typedef unsigned int u32x4 __attribute__((ext_vector_type(4)));

union FragCast { uint4 q; u32x4 u; bf16x8 v; };

__device__ __forceinline__ unsigned int f2bf(float f) {
    unsigned int u = __float_as_uint(f);
    return (u + 0x7FFFu + ((u >> 16) & 1u)) >> 16;
}
__device__ __forceinline__ float bf2f(unsigned short s) {
    return __uint_as_float(((unsigned int)s) << 16);
}

// ---------------------------------------------------------------------------
// k_pack: weights -> bf16 MFMA B-fragments, LANE-MAJOR:
// pk[kt*COLS*32 + ct*512 + l*8 + e] = bf16(W[kt*32 + (l>>4)*8 + e][ct*16+(l&15)])
// ---------------------------------------------------------------------------
__global__ __launch_bounds__(256) void k_pack(
    const float* __restrict__ Wv, const float* __restrict__ Wout,
    const float* __restrict__ Woff, const float* __restrict__ Wattn,
    unsigned short* __restrict__ pkv, unsigned short* __restrict__ pko,
    unsigned short* __restrict__ pkq)
{
    const int tid = blockIdx.x * 256 + threadIdx.x;   // 0..4863
    if (tid < 4096) {
        const float* src = (tid & 2048) ? Wout : Wv;
        unsigned short* dst = (tid & 2048) ? pko : pkv;
        const int rem = tid & 2047;
        const int kt = rem >> 8, col = rem & 255;
        unsigned short* d = dst + (size_t)kt * 8192 + (col >> 4) * 512 + (col & 15) * 8;
        const float* s = src + (size_t)kt * 32 * 256 + col;
#pragma unroll
        for (int j = 0; j < 32; ++j)
            d[(j >> 3) * 128 + (j & 7)] = (unsigned short)f2bf(s[(size_t)j * 256]);
    } else {
        const int rem = tid - 4096;       // 0..767
        const int kt = rem / 96, col = rem % 96;
        unsigned short* d = pkq + (size_t)kt * 3072 + (col >> 4) * 512 + (col & 15) * 8;
        const float* s; int stride;
        if (col < 64) { s = Woff + col; stride = 64; }
        else          { s = Wattn + (col - 64); stride = 32; }
        s += (size_t)kt * 32 * stride;
#pragma unroll
        for (int j = 0; j < 32; ++j)
            d[(j >> 3) * 128 + (j & 7)] = (unsigned short)f2bf(s[(size_t)j * stride]);
    }
}

// ---------------------------------------------------------------------------
// k_vproj: round-12/13 proven. 256 blocks x 512 thr, B frags in regs,
// A dbuf swizzled LDS, ROW-MAJOR bf16 output.
// ---------------------------------------------------------------------------
#define VP_TPB 4
__global__ __launch_bounds__(512) void k_vproj(
    const float* __restrict__ value, const unsigned short* __restrict__ Bpk,
    const float* __restrict__ bv, unsigned short* __restrict__ vproj)
{
    const int t = threadIdx.x;
    const int l = t & 63, w = t >> 6;
    const int mh = w & 1, cg = w >> 1;

    __shared__ unsigned short A[2][64 * 256];

    uint4 bq[8][4];
#pragma unroll
    for (int kt = 0; kt < 8; ++kt)
#pragma unroll
        for (int i = 0; i < 4; ++i)
            bq[kt][i] = *reinterpret_cast<const uint4*>(
                Bpk + (size_t)kt * 8192 + (size_t)(cg * 4 + i) * 512 + l * 8);

    float bb[4];
#pragma unroll
    for (int i = 0; i < 4; ++i) bb[i] = bv[cg * 64 + i * 16 + (l & 15)];

    const size_t tile0 = (size_t)blockIdx.x * VP_TPB;

    float4 st[8];
#pragma unroll
    for (int i = 0; i < 8; ++i) {
        const int chunk = i * 512 + t;
        const int row = chunk >> 6, k0 = (chunk & 63) * 4;
        st[i] = *reinterpret_cast<const float4*>(&value[(tile0 * 64 + row) * NC + k0]);
    }
#pragma unroll
    for (int i = 0; i < 8; ++i) {
        const int chunk = i * 512 + t;
        const int row = chunk >> 6, k0 = (chunk & 63) * 4;
        unsigned int byte = (unsigned int)(row * 512 + k0 * 2) ^ (unsigned int)((row & 7) << 4);
        *reinterpret_cast<uint2*>(reinterpret_cast<char*>(A[0]) + byte) =
            make_uint2(f2bf(st[i].x) | (f2bf(st[i].y) << 16),
                       f2bf(st[i].z) | (f2bf(st[i].w) << 16));
    }
    __syncthreads();

    for (int tt = 0; tt < VP_TPB; ++tt) {
        const int cur = tt & 1;
        if (tt + 1 < VP_TPB) {
#pragma unroll
            for (int i = 0; i < 8; ++i) {
                const int chunk = i * 512 + t;
                const int row = chunk >> 6, k0 = (chunk & 63) * 4;
                st[i] = *reinterpret_cast<const float4*>(
                    &value[((tile0 + tt + 1) * 64 + row) * NC + k0]);
            }
        }

        f32x4 acc[2][4];
#pragma unroll
        for (int m = 0; m < 2; ++m)
#pragma unroll
            for (int i = 0; i < 4; ++i) acc[m][i] = (f32x4)(bb[i]);

#pragma unroll
        for (int kt = 0; kt < 8; ++kt) {
#pragma unroll
            for (int m = 0; m < 2; ++m) {
                const int arow = mh * 32 + m * 16 + (l & 15);
                unsigned int abyte = (unsigned int)(arow * 512 + (kt * 32 + (l >> 4) * 8) * 2)
                                   ^ (unsigned int)((arow & 7) << 4);
                FragCast af;
                af.q = *reinterpret_cast<const uint4*>(reinterpret_cast<const char*>(A[cur]) + abyte);
#pragma unroll
                for (int i = 0; i < 4; ++i) {
                    FragCast bfc; bfc.q = bq[kt][i];
                    acc[m][i] = __builtin_amdgcn_mfma_f32_16x16x32_bf16(af.v, bfc.v, acc[m][i], 0, 0, 0);
                }
            }
        }

        const size_t rowbase = (tile0 + tt) * 64;
#pragma unroll
        for (int m = 0; m < 2; ++m)
#pragma unroll
            for (int i = 0; i < 4; ++i) {
                const int col = cg * 64 + i * 16 + (l & 15);
#pragma unroll
                for (int j = 0; j < 4; ++j) {
                    const size_t row = rowbase + mh * 32 + m * 16 + (l >> 4) * 4 + j;
                    vproj[row * NC + col] = (unsigned short)f2bf(acc[m][i][j]);
                }
            }

        if (tt + 1 < VP_TPB) {
#pragma unroll
            for (int i = 0; i < 8; ++i) {
                const int chunk = i * 512 + t;
                const int row = chunk >> 6, k0 = (chunk & 63) * 4;
                unsigned int byte = (unsigned int)(row * 512 + k0 * 2) ^ (unsigned int)((row & 7) << 4);
                *reinterpret_cast<uint2*>(reinterpret_cast<char*>(A[cur ^ 1]) + byte) =
                    make_uint2(f2bf(st[i].x) | (f2bf(st[i].y) << 16),
                               f2bf(st[i].z) | (f2bf(st[i].w) << 16));
            }
            __syncthreads();
        }
    }
}

// ---------------------------------------------------------------------------
// k_fused (round-13 champion + nontemporal gather loads):
// 16 queries/block, 512 thr / 8 waves, batch->XCD-pair pinned swizzle.
// phase1 offattn MFMA -> LDS; phase2 gather (nt loads, 1 task/thread);
// phase3 outproj MFMA.
// ---------------------------------------------------------------------------
__global__ __launch_bounds__(512) void k_fused(
    const float* __restrict__ query, const float* __restrict__ refp,
    const unsigned short* __restrict__ Bq, const float* __restrict__ boff,
    const float* __restrict__ battn, const unsigned short* __restrict__ vproj,
    const unsigned short* __restrict__ Bo, const float* __restrict__ bout,
    float* __restrict__ out)
{
    const int t = threadIdx.x;
    const int l = t & 63, w = t >> 6;
    const int x = blockIdx.x & 7, kk = blockIdx.x >> 3;
    const int b = x >> 1;                    // batch pinned to XCD pair {2b,2b+1}
    const int j = (kk << 1) | (x & 1);       // 0..511 within batch
    const size_t q0 = (size_t)b * NQ + (size_t)j * 16;

    __shared__ unsigned short A[16 * 256];   // 8 KB: query bf16 (ph1), agg (ph3)
    __shared__ float locs_s[16][64];         // 4 KB
    __shared__ float attn_s[16][32];         // 2 KB
    __shared__ float refs[16][2];

#pragma unroll
    for (int i = 0; i < 2; ++i) {
        const int chunk = i * 512 + t;
        const int row = chunk >> 6, k0 = (chunk & 63) * 4;
        const float4 v4 = *reinterpret_cast<const float4*>(&query[(q0 + row) * NC + k0]);
        unsigned int byte = (unsigned int)(row * 512 + k0 * 2) ^ (unsigned int)((row & 7) << 4);
        *reinterpret_cast<uint2*>(reinterpret_cast<char*>(A) + byte) =
            make_uint2(f2bf(v4.x) | (f2bf(v4.y) << 16),
                       f2bf(v4.z) | (f2bf(v4.w) << 16));
    }
    if (t < 32) reinterpret_cast<float*>(refs)[t] = refp[q0 * 2 + t];
    __syncthreads();

    // ---- phase 1: [offsets|attn] = q @ Wq, waves 0..5 one col-tile each ----
    if (w < 6) {
        const int arow = l & 15, achunk = l >> 4;
        f32x4 acc = (f32x4)(0.f);
#pragma unroll
        for (int kt = 0; kt < 8; ++kt) {
            unsigned int abyte = (unsigned int)(arow * 512 + (kt * 32 + achunk * 8) * 2)
                               ^ (unsigned int)((arow & 7) << 4);
            FragCast af;
            af.q = *reinterpret_cast<const uint4*>(reinterpret_cast<const char*>(A) + abyte);
            FragCast bfc;
            bfc.q = *reinterpret_cast<const uint4*>(Bq + (size_t)kt * 3072 + w * 512 + l * 8);
            acc = __builtin_amdgcn_mfma_f32_16x16x32_bf16(af.v, bfc.v, acc, 0, 0, 0);
        }
        const int col = w * 16 + arow;
        if (col < 64) {
            const float bias = boff[col];
            const int xy = col & 1;
#pragma unroll
            for (int jj = 0; jj < 4; ++jj) {
                const int row = achunk * 4 + jj;
                float off = acc[jj] + bias;
                float loc = refs[row][xy] + off * (0.1f / 128.0f);
                locs_s[row][col] = fminf(fmaxf(loc, 0.f), 1.f);
            }
        } else {
            const int lc = col - 64;
            const float bias = battn[lc];
#pragma unroll
            for (int jj = 0; jj < 4; ++jj) {
                const int row = achunk * 4 + jj;
                float v = acc[jj] + bias;
                float m = fmaxf(v, __shfl_xor(v, 1));
                m = fmaxf(m, __shfl_xor(m, 2));
                float e = __expf(v - m);
                float s = e + __shfl_xor(e, 1);
                s = s + __shfl_xor(s, 2);
                attn_s[row][lc] = e / s;
            }
        }
    }
    __syncthreads();

    // ---- phase 2: gather, one (q,h,c) task per thread, 16 nt loads ----
    {
        const int q = t >> 5, h = (t >> 2) & 7, c = t & 3;
        const char* __restrict__ vb =
            reinterpret_cast<const char*>(vproj) + (size_t)b * NHW * 512;
        const unsigned int laneoff = (unsigned int)(h * 64 + c * 16);

        float wts[16];
        unsigned int offs[16];
#pragma unroll
        for (int p = 0; p < 4; ++p) {
            const float lx = locs_s[q][h * 8 + p * 2 + 0];
            const float ly = locs_s[q][h * 8 + p * 2 + 1];
            const float aw = attn_s[q][h * 4 + p];
            const float xx = lx * (float)IW - 0.5f;
            const float yy = ly * (float)IH - 0.5f;
            const float x0f = floorf(xx), y0f = floorf(yy);
            const float wx = xx - x0f, wy = yy - y0f;
            const int ix0 = (int)x0f, iy0 = (int)y0f;
            const int ix1 = ix0 + 1, iy1 = iy0 + 1;
            const int cx0 = max(ix0, 0), cy0 = max(iy0, 0);
            const int cx1 = min(ix1, IW - 1), cy1 = min(iy1, IH - 1);
            const float vx0 = (ix0 >= 0) ? 1.f : 0.f;
            const float vy0 = (iy0 >= 0) ? 1.f : 0.f;
            const float vx1 = (ix1 < IW) ? 1.f : 0.f;
            const float vy1 = (iy1 < IH) ? 1.f : 0.f;
            wts[p * 4 + 0] = aw * ((1.f - wx) * (1.f - wy) * vx0 * vy0);
            wts[p * 4 + 1] = aw * (wx * (1.f - wy) * vx1 * vy0);
            wts[p * 4 + 2] = aw * ((1.f - wx) * wy * vx0 * vy1);
            wts[p * 4 + 3] = aw * (wx * wy * vx1 * vy1);
            offs[p * 4 + 0] = (unsigned int)(cy0 * IW + cx0) * 512u + laneoff;
            offs[p * 4 + 1] = (unsigned int)(cy0 * IW + cx1) * 512u + laneoff;
            offs[p * 4 + 2] = (unsigned int)(cy1 * IW + cx0) * 512u + laneoff;
            offs[p * 4 + 3] = (unsigned int)(cy1 * IW + cx1) * 512u + laneoff;
        }

        u32x4 vals[16];
#pragma unroll
        for (int jj = 0; jj < 16; ++jj)
            vals[jj] = __builtin_nontemporal_load(
                reinterpret_cast<const u32x4*>(vb + offs[jj]));

        float acc[8];
#pragma unroll
        for (int e = 0; e < 8; ++e) acc[e] = 0.f;
#pragma unroll
        for (int jj = 0; jj < 16; ++jj) {
            const unsigned short* u = reinterpret_cast<const unsigned short*>(&vals[jj]);
            const float wj = wts[jj];
#pragma unroll
            for (int e = 0; e < 8; ++e) acc[e] = fmaf(wj, bf2f(u[e]), acc[e]);
        }

        uint4 pk;
        pk.x = f2bf(acc[0]) | (f2bf(acc[1]) << 16);
        pk.y = f2bf(acc[2]) | (f2bf(acc[3]) << 16);
        pk.z = f2bf(acc[4]) | (f2bf(acc[5]) << 16);
        pk.w = f2bf(acc[6]) | (f2bf(acc[7]) << 16);
        unsigned int byte = (unsigned int)(q * 512 + (h * NHD + c * 8) * 2)
                          ^ (unsigned int)((q & 7) << 4);
        *reinterpret_cast<uint4*>(reinterpret_cast<char*>(A) + byte) = pk;
    }
    __syncthreads();

    // ---- phase 3: out = agg @ Wout + bout, 2 col-tiles per wave ----
    {
        const int arow = l & 15, achunk = l >> 4;
        f32x4 acc2[2];
#pragma unroll
        for (int i = 0; i < 2; ++i) acc2[i] = (f32x4)(0.f);

#pragma unroll
        for (int kt = 0; kt < 8; ++kt) {
            unsigned int abyte = (unsigned int)(arow * 512 + (kt * 32 + achunk * 8) * 2)
                               ^ (unsigned int)((arow & 7) << 4);
            FragCast af;
            af.q = *reinterpret_cast<const uint4*>(reinterpret_cast<const char*>(A) + abyte);
#pragma unroll
            for (int i = 0; i < 2; ++i) {
                const int ct = w * 2 + i;
                FragCast bfc;
                bfc.q = *reinterpret_cast<const uint4*>(Bo + (size_t)kt * 8192 + ct * 512 + l * 8);
                acc2[i] = __builtin_amdgcn_mfma_f32_16x16x32_bf16(af.v, bfc.v, acc2[i], 0, 0, 0);
            }
        }

#pragma unroll
        for (int i = 0; i < 2; ++i) {
            const int col = (w * 2 + i) * 16 + arow;
            const float bbv = bout[col];
#pragma unroll
            for (int jj = 0; jj < 4; ++jj) {
                const size_t row = q0 + achunk * 4 + jj;
                out[row * NC + col] = acc2[i][jj] + bbv;
            }
        }
    }
}

extern "C" void kernel_launch(void* const* d_in, const int* in_sizes, int n_in,
                              void* d_out, int out_size, void* d_ws, size_t ws_size,
                              hipStream_t stream) {
    const float* query = (const float*)d_in[0];
    const float* refp  = (const float*)d_in[1];
    const float* value = (const float*)d_in[2];
    const float* Woff  = (const float*)d_in[3];
    const float* boff  = (const float*)d_in[4];
    const float* Wattn = (const float*)d_in[5];
    const float* battn = (const float*)d_in[6];
    const float* Wv    = (const float*)d_in[7];
    const float* bv    = (const float*)d_in[8];
    const float* Wout  = (const float*)d_in[9];
    const float* bout  = (const float*)d_in[10];
    float* out = (float*)d_out;

    unsigned short* vproj  = (unsigned short*)d_ws;                  // 32 MB row-major
    unsigned short* WvPk   = vproj + (size_t)NB * NHW * NC;          // 128 KB
    unsigned short* WoutPk = WvPk + (size_t)NC * NC;                 // 128 KB
    unsigned short* WqPk   = WoutPk + (size_t)NC * NC;               //  48 KB

    k_pack<<<dim3(19), dim3(256), 0, stream>>>(Wv, Wout, Woff, Wattn, WvPk, WoutPk, WqPk);
    k_vproj<<<dim3(256), dim3(512), 0, stream>>>(value, WvPk, bv, vproj);
    k_fused<<<dim3(NB * NQ / 16), dim3(512), 0, stream>>>(query, refp, WqPk, boff, battn,
                                                          vproj, WoutPk, bout, out);
}

// Round 18
// 67.246 us; speedup vs baseline: 1.4871x; 1.4871x over previous
//
#include <hip/hip_runtime.h>
#include <cstdint>

#define NB 4
#define NQ 8192
#define NC 256
#define IH 128
#define IW 128
#define NHW (IH * IW)
#define NHEADS 8
#define NP 4
#define NHD 32

typedef __bf16 bf16x8 __attribute__((ext_vector_type(8)));
typedef float f32x4 __attribute__((ext_vector_type(4)));

union FragCast { uint4 q; bf16x8 v; };

__device__ __forceinline__ unsigned int f2bf(float f) {
    unsigned int u = __float_as_uint(f);
    return (u + 0x7FFFu + ((u >> 16) & 1u)) >> 16;
}
__device__ __forceinline__ float bf2f(unsigned short s) {
    return __uint_as_float(((unsigned int)s) << 16);
}

// ---------------------------------------------------------------------------
// k_pack: weights -> bf16 MFMA B-fragments, LANE-MAJOR:
// pk[kt*COLS*32 + ct*512 + l*8 + e] = bf16(W[kt*32 + (l>>4)*8 + e][ct*16+(l&15)])
// ---------------------------------------------------------------------------
__global__ __launch_bounds__(256) void k_pack(
    const float* __restrict__ Wv, const float* __restrict__ Wout,
    const float* __restrict__ Woff, const float* __restrict__ Wattn,
    unsigned short* __restrict__ pkv, unsigned short* __restrict__ pko,
    unsigned short* __restrict__ pkq)
{
    const int tid = blockIdx.x * 256 + threadIdx.x;   // 0..4863
    if (tid < 4096) {
        const float* src = (tid & 2048) ? Wout : Wv;
        unsigned short* dst = (tid & 2048) ? pko : pkv;
        const int rem = tid & 2047;
        const int kt = rem >> 8, col = rem & 255;
        unsigned short* d = dst + (size_t)kt * 8192 + (col >> 4) * 512 + (col & 15) * 8;
        const float* s = src + (size_t)kt * 32 * 256 + col;
#pragma unroll
        for (int j = 0; j < 32; ++j)
            d[(j >> 3) * 128 + (j & 7)] = (unsigned short)f2bf(s[(size_t)j * 256]);
    } else {
        const int rem = tid - 4096;       // 0..767
        const int kt = rem / 96, col = rem % 96;
        unsigned short* d = pkq + (size_t)kt * 3072 + (col >> 4) * 512 + (col & 15) * 8;
        const float* s; int stride;
        if (col < 64) { s = Woff + col; stride = 64; }
        else          { s = Wattn + (col - 64); stride = 32; }
        s += (size_t)kt * 32 * stride;
#pragma unroll
        for (int j = 0; j < 32; ++j)
            d[(j >> 3) * 128 + (j & 7)] = (unsigned short)f2bf(s[(size_t)j * stride]);
    }
}

// ---------------------------------------------------------------------------
// k_vproj: 256 blocks x 512 thr (8 waves), 4 tiles of 64 rows per block.
// B frags in registers, A dbuf in swizzled LDS, ROW-MAJOR bf16 output.
// ---------------------------------------------------------------------------
#define VP_TPB 4
__global__ __launch_bounds__(512) void k_vproj(
    const float* __restrict__ value, const unsigned short* __restrict__ Bpk,
    const float* __restrict__ bv, unsigned short* __restrict__ vproj)
{
    const int t = threadIdx.x;
    const int l = t & 63, w = t >> 6;
    const int mh = w & 1, cg = w >> 1;

    __shared__ unsigned short A[2][64 * 256];

    uint4 bq[8][4];
#pragma unroll
    for (int kt = 0; kt < 8; ++kt)
#pragma unroll
        for (int i = 0; i < 4; ++i)
            bq[kt][i] = *reinterpret_cast<const uint4*>(
                Bpk + (size_t)kt * 8192 + (size_t)(cg * 4 + i) * 512 + l * 8);

    float bb[4];
#pragma unroll
    for (int i = 0; i < 4; ++i) bb[i] = bv[cg * 64 + i * 16 + (l & 15)];

    const size_t tile0 = (size_t)blockIdx.x * VP_TPB;

    float4 st[8];
#pragma unroll
    for (int i = 0; i < 8; ++i) {
        const int chunk = i * 512 + t;
        const int row = chunk >> 6, k0 = (chunk & 63) * 4;
        st[i] = *reinterpret_cast<const float4*>(&value[(tile0 * 64 + row) * NC + k0]);
    }
#pragma unroll
    for (int i = 0; i < 8; ++i) {
        const int chunk = i * 512 + t;
        const int row = chunk >> 6, k0 = (chunk & 63) * 4;
        unsigned int byte = (unsigned int)(row * 512 + k0 * 2) ^ (unsigned int)((row & 7) << 4);
        *reinterpret_cast<uint2*>(reinterpret_cast<char*>(A[0]) + byte) =
            make_uint2(f2bf(st[i].x) | (f2bf(st[i].y) << 16),
                       f2bf(st[i].z) | (f2bf(st[i].w) << 16));
    }
    __syncthreads();

    for (int tt = 0; tt < VP_TPB; ++tt) {
        const int cur = tt & 1;
        if (tt + 1 < VP_TPB) {
#pragma unroll
            for (int i = 0; i < 8; ++i) {
                const int chunk = i * 512 + t;
                const int row = chunk >> 6, k0 = (chunk & 63) * 4;
                st[i] = *reinterpret_cast<const float4*>(
                    &value[((tile0 + tt + 1) * 64 + row) * NC + k0]);
            }
        }

        f32x4 acc[2][4];
#pragma unroll
        for (int m = 0; m < 2; ++m)
#pragma unroll
            for (int i = 0; i < 4; ++i) acc[m][i] = (f32x4)(bb[i]);

#pragma unroll
        for (int kt = 0; kt < 8; ++kt) {
#pragma unroll
            for (int m = 0; m < 2; ++m) {
                const int arow = mh * 32 + m * 16 + (l & 15);
                unsigned int abyte = (unsigned int)(arow * 512 + (kt * 32 + (l >> 4) * 8) * 2)
                                   ^ (unsigned int)((arow & 7) << 4);
                FragCast af;
                af.q = *reinterpret_cast<const uint4*>(reinterpret_cast<const char*>(A[cur]) + abyte);
#pragma unroll
                for (int i = 0; i < 4; ++i) {
                    FragCast bfc; bfc.q = bq[kt][i];
                    acc[m][i] = __builtin_amdgcn_mfma_f32_16x16x32_bf16(af.v, bfc.v, acc[m][i], 0, 0, 0);
                }
            }
        }

        const size_t rowbase = (tile0 + tt) * 64;
#pragma unroll
        for (int m = 0; m < 2; ++m)
#pragma unroll
            for (int i = 0; i < 4; ++i) {
                const int col = cg * 64 + i * 16 + (l & 15);
#pragma unroll
                for (int j = 0; j < 4; ++j) {
                    const size_t row = rowbase + mh * 32 + m * 16 + (l >> 4) * 4 + j;
                    vproj[row * NC + col] = (unsigned short)f2bf(acc[m][i][j]);
                }
            }

        if (tt + 1 < VP_TPB) {
#pragma unroll
            for (int i = 0; i < 8; ++i) {
                const int chunk = i * 512 + t;
                const int row = chunk >> 6, k0 = (chunk & 63) * 4;
                unsigned int byte = (unsigned int)(row * 512 + k0 * 2) ^ (unsigned int)((row & 7) << 4);
                *reinterpret_cast<uint2*>(reinterpret_cast<char*>(A[cur ^ 1]) + byte) =
                    make_uint2(f2bf(st[i].x) | (f2bf(st[i].y) << 16),
                               f2bf(st[i].z) | (f2bf(st[i].w) << 16));
            }
            __syncthreads();
        }
    }
}

// ---------------------------------------------------------------------------
// k_fused (round-13 champion): 16 queries/block, 512 thr / 8 waves,
// batch->XCD-pair pinned swizzle. phase1 offattn MFMA -> LDS;
// phase2 gather (1 task/thread, 16 loads); phase3 outproj MFMA.
// ---------------------------------------------------------------------------
__global__ __launch_bounds__(512) void k_fused(
    const float* __restrict__ query, const float* __restrict__ refp,
    const unsigned short* __restrict__ Bq, const float* __restrict__ boff,
    const float* __restrict__ battn, const unsigned short* __restrict__ vproj,
    const unsigned short* __restrict__ Bo, const float* __restrict__ bout,
    float* __restrict__ out)
{
    const int t = threadIdx.x;
    const int l = t & 63, w = t >> 6;
    const int x = blockIdx.x & 7, kk = blockIdx.x >> 3;
    const int b = x >> 1;                    // batch pinned to XCD pair {2b,2b+1}
    const int j = (kk << 1) | (x & 1);       // 0..511 within batch
    const size_t q0 = (size_t)b * NQ + (size_t)j * 16;

    __shared__ unsigned short A[16 * 256];   // 8 KB: query bf16 (ph1), agg (ph3)
    __shared__ float locs_s[16][64];         // 4 KB
    __shared__ float attn_s[16][32];         // 2 KB
    __shared__ float refs[16][2];

#pragma unroll
    for (int i = 0; i < 2; ++i) {
        const int chunk = i * 512 + t;
        const int row = chunk >> 6, k0 = (chunk & 63) * 4;
        const float4 v4 = *reinterpret_cast<const float4*>(&query[(q0 + row) * NC + k0]);
        unsigned int byte = (unsigned int)(row * 512 + k0 * 2) ^ (unsigned int)((row & 7) << 4);
        *reinterpret_cast<uint2*>(reinterpret_cast<char*>(A) + byte) =
            make_uint2(f2bf(v4.x) | (f2bf(v4.y) << 16),
                       f2bf(v4.z) | (f2bf(v4.w) << 16));
    }
    if (t < 32) reinterpret_cast<float*>(refs)[t] = refp[q0 * 2 + t];
    __syncthreads();

    // ---- phase 1: [offsets|attn] = q @ Wq, waves 0..5 one col-tile each ----
    if (w < 6) {
        const int arow = l & 15, achunk = l >> 4;
        f32x4 acc = (f32x4)(0.f);
#pragma unroll
        for (int kt = 0; kt < 8; ++kt) {
            unsigned int abyte = (unsigned int)(arow * 512 + (kt * 32 + achunk * 8) * 2)
                               ^ (unsigned int)((arow & 7) << 4);
            FragCast af;
            af.q = *reinterpret_cast<const uint4*>(reinterpret_cast<const char*>(A) + abyte);
            FragCast bfc;
            bfc.q = *reinterpret_cast<const uint4*>(Bq + (size_t)kt * 3072 + w * 512 + l * 8);
            acc = __builtin_amdgcn_mfma_f32_16x16x32_bf16(af.v, bfc.v, acc, 0, 0, 0);
        }
        const int col = w * 16 + arow;
        if (col < 64) {
            const float bias = boff[col];
            const int xy = col & 1;
#pragma unroll
            for (int jj = 0; jj < 4; ++jj) {
                const int row = achunk * 4 + jj;
                float off = acc[jj] + bias;
                float loc = refs[row][xy] + off * (0.1f / 128.0f);
                locs_s[row][col] = fminf(fmaxf(loc, 0.f), 1.f);
            }
        } else {
            const int lc = col - 64;
            const float bias = battn[lc];
#pragma unroll
            for (int jj = 0; jj < 4; ++jj) {
                const int row = achunk * 4 + jj;
                float v = acc[jj] + bias;
                float m = fmaxf(v, __shfl_xor(v, 1));
                m = fmaxf(m, __shfl_xor(m, 2));
                float e = __expf(v - m);
                float s = e + __shfl_xor(e, 1);
                s = s + __shfl_xor(s, 2);
                attn_s[row][lc] = e / s;
            }
        }
    }
    __syncthreads();

    // ---- phase 2: gather, one (q,h,c) task per thread, 16 loads ----
    {
        const int q = t >> 5, h = (t >> 2) & 7, c = t & 3;
        const char* __restrict__ vb =
            reinterpret_cast<const char*>(vproj) + (size_t)b * NHW * 512;
        const unsigned int laneoff = (unsigned int)(h * 64 + c * 16);

        float wts[16];
        unsigned int offs[16];
#pragma unroll
        for (int p = 0; p < 4; ++p) {
            const float lx = locs_s[q][h * 8 + p * 2 + 0];
            const float ly = locs_s[q][h * 8 + p * 2 + 1];
            const float aw = attn_s[q][h * 4 + p];
            const float xx = lx * (float)IW - 0.5f;
            const float yy = ly * (float)IH - 0.5f;
            const float x0f = floorf(xx), y0f = floorf(yy);
            const float wx = xx - x0f, wy = yy - y0f;
            const int ix0 = (int)x0f, iy0 = (int)y0f;
            const int ix1 = ix0 + 1, iy1 = iy0 + 1;
            const int cx0 = max(ix0, 0), cy0 = max(iy0, 0);
            const int cx1 = min(ix1, IW - 1), cy1 = min(iy1, IH - 1);
            const float vx0 = (ix0 >= 0) ? 1.f : 0.f;
            const float vy0 = (iy0 >= 0) ? 1.f : 0.f;
            const float vx1 = (ix1 < IW) ? 1.f : 0.f;
            const float vy1 = (iy1 < IH) ? 1.f : 0.f;
            wts[p * 4 + 0] = aw * ((1.f - wx) * (1.f - wy) * vx0 * vy0);
            wts[p * 4 + 1] = aw * (wx * (1.f - wy) * vx1 * vy0);
            wts[p * 4 + 2] = aw * ((1.f - wx) * wy * vx0 * vy1);
            wts[p * 4 + 3] = aw * (wx * wy * vx1 * vy1);
            offs[p * 4 + 0] = (unsigned int)(cy0 * IW + cx0) * 512u + laneoff;
            offs[p * 4 + 1] = (unsigned int)(cy0 * IW + cx1) * 512u + laneoff;
            offs[p * 4 + 2] = (unsigned int)(cy1 * IW + cx0) * 512u + laneoff;
            offs[p * 4 + 3] = (unsigned int)(cy1 * IW + cx1) * 512u + laneoff;
        }

        uint4 vals[16];
#pragma unroll
        for (int jj = 0; jj < 16; ++jj)
            vals[jj] = *reinterpret_cast<const uint4*>(vb + offs[jj]);

        float acc[8];
#pragma unroll
        for (int e = 0; e < 8; ++e) acc[e] = 0.f;
#pragma unroll
        for (int jj = 0; jj < 16; ++jj) {
            const unsigned short* u = reinterpret_cast<const unsigned short*>(&vals[jj]);
            const float wj = wts[jj];
#pragma unroll
            for (int e = 0; e < 8; ++e) acc[e] = fmaf(wj, bf2f(u[e]), acc[e]);
        }

        uint4 pk;
        pk.x = f2bf(acc[0]) | (f2bf(acc[1]) << 16);
        pk.y = f2bf(acc[2]) | (f2bf(acc[3]) << 16);
        pk.z = f2bf(acc[4]) | (f2bf(acc[5]) << 16);
        pk.w = f2bf(acc[6]) | (f2bf(acc[7]) << 16);
        unsigned int byte = (unsigned int)(q * 512 + (h * NHD + c * 8) * 2)
                          ^ (unsigned int)((q & 7) << 4);
        *reinterpret_cast<uint4*>(reinterpret_cast<char*>(A) + byte) = pk;
    }
    __syncthreads();

    // ---- phase 3: out = agg @ Wout + bout, 2 col-tiles per wave ----
    {
        const int arow = l & 15, achunk = l >> 4;
        f32x4 acc2[2];
#pragma unroll
        for (int i = 0; i < 2; ++i) acc2[i] = (f32x4)(0.f);

#pragma unroll
        for (int kt = 0; kt < 8; ++kt) {
            unsigned int abyte = (unsigned int)(arow * 512 + (kt * 32 + achunk * 8) * 2)
                               ^ (unsigned int)((arow & 7) << 4);
            FragCast af;
            af.q = *reinterpret_cast<const uint4*>(reinterpret_cast<const char*>(A) + abyte);
#pragma unroll
            for (int i = 0; i < 2; ++i) {
                const int ct = w * 2 + i;
                FragCast bfc;
                bfc.q = *reinterpret_cast<const uint4*>(Bo + (size_t)kt * 8192 + ct * 512 + l * 8);
                acc2[i] = __builtin_amdgcn_mfma_f32_16x16x32_bf16(af.v, bfc.v, acc2[i], 0, 0, 0);
            }
        }

#pragma unroll
        for (int i = 0; i < 2; ++i) {
            const int col = (w * 2 + i) * 16 + arow;
            const float bbv = bout[col];
#pragma unroll
            for (int jj = 0; jj < 4; ++jj) {
                const size_t row = q0 + achunk * 4 + jj;
                out[row * NC + col] = acc2[i][jj] + bbv;
            }
        }
    }
}

extern "C" void kernel_launch(void* const* d_in, const int* in_sizes, int n_in,
                              void* d_out, int out_size, void* d_ws, size_t ws_size,
                              hipStream_t stream) {
    const float* query = (const float*)d_in[0];
    const float* refp  = (const float*)d_in[1];
    const float* value = (const float*)d_in[2];
    const float* Woff  = (const float*)d_in[3];
    const float* boff  = (const float*)d_in[4];
    const float* Wattn = (const float*)d_in[5];
    const float* battn = (const float*)d_in[6];
    const float* Wv    = (const float*)d_in[7];
    const float* bv    = (const float*)d_in[8];
    const float* Wout  = (const float*)d_in[9];
    const float* bout  = (const float*)d_in[10];
    float* out = (float*)d_out;

    unsigned short* vproj  = (unsigned short*)d_ws;                  // 32 MB row-major
    unsigned short* WvPk   = vproj + (size_t)NB * NHW * NC;          // 128 KB
    unsigned short* WoutPk = WvPk + (size_t)NC * NC;                 // 128 KB
    unsigned short* WqPk   = WoutPk + (size_t)NC * NC;               //  48 KB

    k_pack<<<dim3(19), dim3(256), 0, stream>>>(Wv, Wout, Woff, Wattn, WvPk, WoutPk, WqPk);
    k_vproj<<<dim3(256), dim3(512), 0, stream>>>(value, WvPk, bv, vproj);
    k_fused<<<dim3(NB * NQ / 16), dim3(512), 0, stream>>>(query, refp, WqPk, boff, battn,
                                                          vproj, WoutPk, bout, out);
}